// Round 2
// baseline (164.659 us; speedup 1.0000x reference)
//
#include <hip/hip_runtime.h>
#include <stdint.h>

typedef _Float16 half4v __attribute__((ext_vector_type(4)));
typedef _Float16 half8v __attribute__((ext_vector_type(8)));
typedef float    f32x4  __attribute__((ext_vector_type(4)));

#define NB 8
#define SXX 2048
#define SYY 2048
#define DD 512
#define QBLK 64
#define TBLK 64
#define NDT 32                 /* D/16 d-tiles */
#define NITER (SYY / TBLK)     /* 32 */

/* LDS: plain row-major y tile, fp16, padded rows: 520 f16 = 1040 B.
   1040/4 = 260 ≡ 4 (mod 32 banks) -> rows rotate banks by 4.
   Derived: staging b128 writes, QK^T b128 reads, tr b64 reads all at
   conflict-free floor. */
#define RSB 1040u
#define LDS_BYTES (64 * 1040)  /* 66560 B */

__global__ __launch_bounds__(256, 1)
void attn_fused(const float* __restrict__ x, const float* __restrict__ y,
                float* __restrict__ out) {
  extern __shared__ char smem[];
  const int bid   = blockIdx.x;
  const int b     = bid & 7;      /* one batch per XCD -> y tile L2-resident */
  const int qtile = bid >> 3;
  const int tid   = threadIdx.x;
  const int wave  = tid >> 6;
  const int lane  = tid & 63;
  const int l15   = lane & 15;
  const int g     = lane >> 4;

  const float* xb = x + (size_t)b * SXX * DD;
  const float* yb = y + (size_t)b * SYY * DD;
  float* outb     = out + (size_t)b * SXX * (2 * DD);
  const int qbase = qtile * QBLK;

  /* ---- out[:, :512] = x (exact fp32 copy) ---- */
  {
    const f32x4* src = (const f32x4*)(xb + (size_t)qbase * DD);
    for (int i = tid; i < QBLK * (DD / 4); i += 256) {
      f32x4 v = src[i];
      const int row = i >> 7;
      const int c4  = i & 127;
      *(f32x4*)(outb + (size_t)(qbase + row) * (2 * DD) + c4 * 4) = v;
    }
  }

  /* ---- Q fragments (fp16), B-operand of 16x16x32:
     lane holds col q = qbase+16*wave+l15, elems d = 32c + 8g + j ---- */
  const int qrow = qbase + wave * 16 + l15;
  half8v bq[16];
  {
    const float* xr = xb + (size_t)qrow * DD;
#pragma unroll
    for (int c = 0; c < 16; ++c) {
      const int d0 = c * 32 + g * 8;
      f32x4 f0 = *(const f32x4*)(xr + d0);
      f32x4 f1 = *(const f32x4*)(xr + d0 + 4);
      half8v h;
      h[0] = (_Float16)f0[0]; h[1] = (_Float16)f0[1];
      h[2] = (_Float16)f0[2]; h[3] = (_Float16)f0[3];
      h[4] = (_Float16)f1[0]; h[5] = (_Float16)f1[1];
      h[6] = (_Float16)f1[2]; h[7] = (_Float16)f1[3];
      bq[c] = h;
    }
  }

  f32x4 acc[NDT];
#pragma unroll
  for (int i = 0; i < NDT; ++i) acc[i] = (f32x4){0.f, 0.f, 0.f, 0.f};
  float mrun = -3.0e38f;
  float lrun = 0.0f;

  for (int it = 0; it < NITER; ++it) {
    /* ---- stage y tile (fp32 -> fp16, row-major padded).
       unit = 8 d's of one row: 2x f32x4 coalesced load, 1x ds_write_b128 */
    {
      const float* ybt = yb + (size_t)it * TBLK * DD;
#pragma unroll
      for (int k = 0; k < 16; ++k) {
        const int u  = tid + k * 256;
        const int t  = u >> 6;
        const int c8 = u & 63;
        const float* p = ybt + t * DD + c8 * 8;
        f32x4 f0 = *(const f32x4*)(p);
        f32x4 f1 = *(const f32x4*)(p + 4);
        half8v h;
        h[0]=(_Float16)f0[0]; h[1]=(_Float16)f0[1]; h[2]=(_Float16)f0[2]; h[3]=(_Float16)f0[3];
        h[4]=(_Float16)f1[0]; h[5]=(_Float16)f1[1]; h[6]=(_Float16)f1[2]; h[7]=(_Float16)f1[3];
        *(half8v*)(smem + (uint32_t)t * RSB + (uint32_t)c8 * 16u) = h;
      }
    }
    __syncthreads();

    /* ---- QK^T swapped: S^T = mfma(A=y, B=x), 4 independent 16t chains.
       A: lane holds row t = tt*16 + l15, elems d = 32c + 8g + j.
       C: lane holds q = l15 (col), t = 16tt + 4g + r (row). ---- */
    f32x4 st[4];
#pragma unroll
    for (int tt = 0; tt < 4; ++tt) st[tt] = (f32x4){0.f, 0.f, 0.f, 0.f};
#pragma unroll
    for (int c = 0; c < 16; ++c) {
      const uint32_t db = 64u * (uint32_t)c + 16u * (uint32_t)g;
#pragma unroll
      for (int tt = 0; tt < 4; ++tt) {
        const half8v af =
            *(const half8v*)(smem + (uint32_t)(tt * 16 + l15) * RSB + db);
        st[tt] = __builtin_amdgcn_mfma_f32_16x16x32_f16(af, bq[c], st[tt], 0, 0, 0);
      }
    }

    /* ---- online softmax over t, per q = l15 (replicated over 4 groups) */
    float tmax = -3.0e38f;
#pragma unroll
    for (int tt = 0; tt < 4; ++tt) {
#pragma unroll
      for (int r = 0; r < 4; ++r) tmax = fmaxf(tmax, st[tt][r]);
    }
    tmax = fmaxf(tmax, __shfl_xor(tmax, 16));
    tmax = fmaxf(tmax, __shfl_xor(tmax, 32));
    const float mnew = fmaxf(mrun, tmax);
    const bool  need = (mnew > mrun);
    float pvv[16];
    float rsum = 0.f;
#pragma unroll
    for (int tt = 0; tt < 4; ++tt) {
#pragma unroll
      for (int r = 0; r < 4; ++r) {
        const float e = __expf(st[tt][r] - mnew);
        pvv[tt * 4 + r] = e;
        rsum += e;
      }
    }
    rsum += __shfl_xor(rsum, 16);
    rsum += __shfl_xor(rsum, 32);
    const float scale = __expf(mrun - mnew);
    lrun = lrun * scale + rsum;
    mrun = mnew;

    if (__any(need)) {
      float rs[4];
#pragma unroll
      for (int r = 0; r < 4; ++r) rs[r] = __shfl(scale, 4 * g + r);
#pragma unroll
      for (int dt = 0; dt < NDT; ++dt) {
        acc[dt][0] *= rs[0]; acc[dt][1] *= rs[1];
        acc[dt][2] *= rs[2]; acc[dt][3] *= rs[3];
      }
    }

    /* ---- P A-fragments for 16x16x32: pa8[p][j]:
       j<4 -> P[q][32p + 4g + j], j>=4 -> P[q][32p + 16 + 4g + (j-4)] ---- */
    half8v pa8[2];
#pragma unroll
    for (int j = 0; j < 8; ++j) {
      pa8[0][j] = (_Float16)pvv[j];
      pa8[1][j] = (_Float16)pvv[8 + j];
    }

    /* ---- PV: V B-fragments via positional tr-read:
       lane (g,l15) supplies addr of ITS 8 contiguous bytes
       V[16tt + 4g + (l15>>2)][16dt + 4*(l15&3)]; crossbar delivers
       elem j = V[16tt + 4g + j][16dt + l15]. 3-deep pipelined. ---- */
    {
      const uint32_t rb = (uint32_t)(4 * g + (l15 >> 2)) * RSB +
                          (uint32_t)(l15 & 3) * 8u;
      half4v trv[3][4];
#pragma unroll
      for (int dt = 0; dt < NDT + 2; ++dt) {
        if (dt < NDT) {
          const uint32_t a = rb + (uint32_t)dt * 32u;
          const int s = dt % 3;
          asm volatile("ds_read_b64_tr_b16 %0, %1" : "=v"(trv[s][0]) : "v"(a));
          asm volatile("ds_read_b64_tr_b16 %0, %1" : "=v"(trv[s][1]) : "v"(a + 16u * RSB));
          asm volatile("ds_read_b64_tr_b16 %0, %1" : "=v"(trv[s][2]) : "v"(a + 32u * RSB));
          asm volatile("ds_read_b64_tr_b16 %0, %1" : "=v"(trv[s][3]) : "v"(a + 48u * RSB));
        }
        if (dt >= 2) {
          if (dt < NDT) {
            asm volatile("s_waitcnt lgkmcnt(8)" ::: "memory");
          } else if (dt == NDT) {
            asm volatile("s_waitcnt lgkmcnt(4)" ::: "memory");
          } else {
            asm volatile("s_waitcnt lgkmcnt(0)" ::: "memory");
          }
          __builtin_amdgcn_sched_barrier(0);
          const int dd = dt - 2;
          const int s = dd % 3;
          const half8v b0 = __builtin_shufflevector(trv[s][0], trv[s][1],
                                                    0, 1, 2, 3, 4, 5, 6, 7);
          const half8v b1 = __builtin_shufflevector(trv[s][2], trv[s][3],
                                                    0, 1, 2, 3, 4, 5, 6, 7);
          acc[dd] = __builtin_amdgcn_mfma_f32_16x16x32_f16(pa8[0], b0, acc[dd], 0, 0, 0);
          acc[dd] = __builtin_amdgcn_mfma_f32_16x16x32_f16(pa8[1], b1, acc[dd], 0, 0, 0);
        }
      }
    }
    __syncthreads();
  }

  /* ---- epilogue: normalize and store a into out[:, 512:] ---- */
  float inv[4];
#pragma unroll
  for (int r = 0; r < 4; ++r) inv[r] = 1.0f / __shfl(lrun, 4 * g + r);
#pragma unroll
  for (int dt = 0; dt < NDT; ++dt) {
#pragma unroll
    for (int r = 0; r < 4; ++r) {
      const int q = qbase + wave * 16 + 4 * g + r;
      outb[(size_t)q * (2 * DD) + DD + dt * 16 + l15] = acc[dt][r] * inv[r];
    }
  }
}

extern "C" void kernel_launch(void* const* d_in, const int* in_sizes, int n_in,
                              void* d_out, int out_size, void* d_ws, size_t ws_size,
                              hipStream_t stream) {
  (void)in_sizes; (void)n_in; (void)out_size; (void)d_ws; (void)ws_size;
  const float* x = (const float*)d_in[0];
  const float* y = (const float*)d_in[1];
  float* out = (float*)d_out;
  static_assert(LDS_BYTES <= 160 * 1024, "LDS over budget");
  hipFuncSetAttribute((const void*)attn_fused,
                      hipFuncAttributeMaxDynamicSharedMemorySize, LDS_BYTES);
  hipLaunchKernelGGL(attn_fused, dim3((SXX / QBLK) * NB), dim3(256), LDS_BYTES,
                     stream, x, y, out);
}